// Round 10
// baseline (247.933 us; speedup 1.0000x reference)
//
#include <hip/hip_runtime.h>
#include <hip/hip_bf16.h>
#include <math.h>

#define EPSF 1e-5f
#define SELHI 0x05040100u
#define SELLO 0x07060302u

typedef __attribute__((ext_vector_type(8))) short bf16x8;
typedef __attribute__((ext_vector_type(16))) float f32x16;

// pack float -> u32 { low16 = hi-bf16 (truncated), high16 = lo-bf16 (residual) }
__device__ __forceinline__ uint32_t packsplit(float x) {
  uint32_t xb = __builtin_bit_cast(uint32_t, x);
  float hi = __builtin_bit_cast(float, xb & 0xFFFF0000u);
  float resid = x - hi;
  return __builtin_amdgcn_perm(__builtin_bit_cast(uint32_t, resid), xb, 0x07060302u);
}

// 8 packed u32 -> one 8xbf16 fragment (SELHI = hi halves, SELLO = residuals)
__device__ __forceinline__ uint4 mkfrag8(const uint32_t* p, uint32_t sel) {
  uint4 u;
  u.x = __builtin_amdgcn_perm(p[1], p[0], sel);
  u.y = __builtin_amdgcn_perm(p[3], p[2], sel);
  u.z = __builtin_amdgcn_perm(p[5], p[4], sel);
  u.w = __builtin_amdgcn_perm(p[7], p[6], sel);
  return u;
}

__device__ __forceinline__ f32x16 mf(uint4 a, uint4 b, f32x16 c) {
  return __builtin_amdgcn_mfma_f32_32x32x16_bf16(
      __builtin_bit_cast(bf16x8, a), __builtin_bit_cast(bf16x8, b), c, 0, 0, 0);
}

#define F4C(v, i) ((i) == 0 ? (v).x : (i) == 1 ? (v).y : (i) == 2 ? (v).z : (v).w)

// =====================================================================
// Kernel 0: qa fragment precompute (batch-independent addresses ->
//   MFMA B-fragment table, 512 KB, built once).
// =====================================================================
__global__ __launch_bounds__(64) void qa_pack_kernel(
    const float* __restrict__ addresses, uint32_t* __restrict__ qaF)
{
  const int T = blockIdx.x;
  const int lane = threadIdx.x;
  const int g32 = lane >> 5, c32 = lane & 31;
  #pragma unroll
  for (int ks = 0; ks < 4; ++ks) {
    const float* ap = addresses + (size_t)(T*32 + c32)*64 + ks*16 + g32*8;
    float4 f0 = *(const float4*)ap;
    float4 f1 = *(const float4*)(ap + 4);
    uint32_t qp[8] = {
      packsplit(fmaxf(f0.x,0.f)), packsplit(fmaxf(f0.y,0.f)),
      packsplit(fmaxf(f0.z,0.f)), packsplit(fmaxf(f0.w,0.f)),
      packsplit(fmaxf(f1.x,0.f)), packsplit(fmaxf(f1.y,0.f)),
      packsplit(fmaxf(f1.z,0.f)), packsplit(fmaxf(f1.w,0.f)) };
    *(uint4*)&qaF[(size_t)T*2048 + (ks*2+0)*256 + lane*4] = mkfrag8(qp, SELHI);
    *(uint4*)&qaF[(size_t)T*2048 + (ks*2+1)*256 + lane*4] = mkfrag8(qp, SELLO);
  }
}

// =====================================================================
// Kernel 1: fused projection GEMM (unchanged)
// =====================================================================
__global__ __launch_bounds__(256) void proj_gemm_kernel(
    const float* __restrict__ x,
    const float* __restrict__ Wk, const float* __restrict__ bk,
    const float* __restrict__ Wv, const float* __restrict__ bv,
    const float* __restrict__ Wq, const float* __restrict__ bq,
    float* __restrict__ proj)
{
  __shared__ float As[16][68];
  __shared__ float Bs[16][68];
  const int col0 = blockIdx.x * 64;
  const int row0 = blockIdx.y * 64;
  const float* Bp; const float* bias; int ldb, bcol, relu;
  if (col0 < 512)       { Bp = Wk; bias = bk; ldb = 512;  bcol = col0;        relu = 1; }
  else if (col0 < 1536) { Bp = Wv; bias = bv; ldb = 1024; bcol = col0 - 512;  relu = 0; }
  else                  { Bp = Wq; bias = bq; ldb = 512;  bcol = col0 - 1536; relu = 1; }
  const int tid = threadIdx.x;
  const int tr = tid >> 4, tc = tid & 15;
  float acc[4][4] = {};
  for (int k0 = 0; k0 < 1024; k0 += 16) {
    {
      int r = tid >> 2, kk = (tid & 3) << 2;
      float4 a4 = *(const float4*)&x[(size_t)(row0 + r) * 1024 + k0 + kk];
      As[kk+0][r] = a4.x; As[kk+1][r] = a4.y; As[kk+2][r] = a4.z; As[kk+3][r] = a4.w;
    }
    {
      int kr = tid >> 4, cc = (tid & 15) << 2;
      *(float4*)&Bs[kr][cc] = *(const float4*)&Bp[(size_t)(k0 + kr) * ldb + bcol + cc];
    }
    __syncthreads();
    #pragma unroll
    for (int k = 0; k < 16; ++k) {
      float4 av4 = *(const float4*)&As[k][tr*4];
      float4 bv4 = *(const float4*)&Bs[k][tc*4];
      float av[4] = {av4.x, av4.y, av4.z, av4.w};
      float bb[4] = {bv4.x, bv4.y, bv4.z, bv4.w};
      #pragma unroll
      for (int i = 0; i < 4; ++i)
        #pragma unroll
        for (int j = 0; j < 4; ++j)
          acc[i][j] = fmaf(av[i], bb[j], acc[i][j]);
    }
    __syncthreads();
  }
  #pragma unroll
  for (int i = 0; i < 4; ++i) {
    int r = row0 + tr*4 + i;
    #pragma unroll
    for (int j = 0; j < 4; ++j) {
      int cl = tc*4 + j;
      float v = acc[i][j] + bias[bcol + cl];
      if (relu) v = fmaxf(v, 0.f);
      proj[(size_t)r * 2048 + col0 + cl] = v;
    }
  }
}

// =====================================================================
// Kernel 2: fused memory kernel, R9 = R8 minus 48 registers.
//   - qn loads moved to just before C-half0 (live one phase, not four)
//   - E half-0 loaded inline in ELEM (L1-hot, still before M_ issue)
//   - E half-1 preload shrunk to 4 x float4
//   R8's rcp + qaF-table VALU cuts retained. Goal: zero scratch.
// =====================================================================
__global__ __launch_bounds__(256, 2) void fused_mem_kernel(
    const float* __restrict__ memories,   // [512][2048][64]
    const float* __restrict__ addresses,  // [2048][64]
    const float* __restrict__ proj,       // [512][2048] = fk|v|fq
    const uint32_t* __restrict__ qaF,     // [64][8][64][4] qa fragments
    float* __restrict__ attn)             // [512][512]
{
  // 80 KB arena:
  //  [0,2048)      fkFrag   (epilogue: n2stage/norm2/den2 overlay)
  //  [2048,4096)   vFrag
  //  [4096,20480)  pk region: 4 waves x { pF[32][64], pN[32][64] }
  __shared__ uint32_t SH[20480];

  const int b = blockIdx.x, tid = threadIdx.x;
  const int wave = tid >> 6, lane = tid & 63;
  const int g32 = lane >> 5, c32 = lane & 31;

  uint32_t* fkFrag = SH;
  uint32_t* vFrag  = SH + 2048;
  uint32_t* pkbase = SH + 4096;
  uint32_t* pF = pkbase + wave * 4096;   // [32][64] u32, col ^= (row&7)<<2
  uint32_t* pN = pF + 2048;

  // ---- stage proj row (pbuf overlays pk region) ----
  float* pbuf = (float*)pkbase;
  {
    const float* prow = proj + (size_t)b * 2048;
    *(float4*)&pbuf[tid*8]   = *(const float4*)&prow[tid*8];
    *(float4*)&pbuf[tid*8+4] = *(const float4*)&prow[tid*8+4];
  }
  __syncthreads();

  // ---- one-time fragment packing (wave w: kstep w, e-tile w) ----
  {
    const int ks = wave;
    float4 f0 = *(const float4*)&pbuf[c32*64 + ks*16 + g32*8];
    float4 f1 = *(const float4*)&pbuf[c32*64 + ks*16 + g32*8 + 4];
    uint32_t p[8] = { packsplit(f0.x), packsplit(f0.y), packsplit(f0.z), packsplit(f0.w),
                      packsplit(f1.x), packsplit(f1.y), packsplit(f1.z), packsplit(f1.w) };
    *(uint4*)&fkFrag[((ks*2+0)*64 + lane)*4] = mkfrag8(p, SELHI);
    *(uint4*)&fkFrag[((ks*2+1)*64 + lane)*4] = mkfrag8(p, SELLO);
    const int t = wave;
    uint32_t q[8];
    #pragma unroll
    for (int j = 0; j < 8; ++j) {
      int h = (g32*8 + j) & 7;
      q[j] = packsplit(pbuf[512 + h*128 + t*32 + c32]);
    }
    *(uint4*)&vFrag[((t*2+0)*64 + lane)*4] = mkfrag8(q, SELHI);
    *(uint4*)&vFrag[((t*2+1)*64 + lane)*4] = mkfrag8(q, SELLO);
  }
  __syncthreads();

  f32x16 Zv;
  #pragma unroll
  for (int r = 0; r < 16; ++r) Zv[r] = 0.f;
  f32x16 aD00 = Zv, aD01 = Zv, aD10 = Zv, aD11 = Zv;
  float n2a[32];
  #pragma unroll
  for (int k = 0; k < 32; ++k) n2a[k] = 0.f;

  const float* aRow0 = addresses + (size_t)(wave*512 + c32) * 64;
  const float* mRow0 = memories + ((size_t)b*2048 + wave*512 + c32) * 64;
  const uint32_t* qaBase = qaF + (size_t)(wave*16)*2048 + lane*4;

  auto do_mfma = [&](int base) {
    uint32_t rf0[8], rf1[8], rn0[8], rn1[8];
    #pragma unroll
    for (int e = 0; e < 8; ++e) {
      const int row = base + g32*8 + e;
      const int cs = c32 ^ ((row & 7) << 2);
      rf0[e] = pF[row*64 + cs];
      rf1[e] = pF[row*64 + 32 + cs];
      rn0[e] = pN[row*64 + cs];
      rn1[e] = pN[row*64 + 32 + cs];
    }
    uint4 A0h = mkfrag8(rf0, SELHI), A0l = mkfrag8(rf0, SELLO);
    uint4 A1h = mkfrag8(rf1, SELHI), A1l = mkfrag8(rf1, SELLO);
    uint4 B0h = mkfrag8(rn0, SELHI), B0l = mkfrag8(rn0, SELLO);
    uint4 B1h = mkfrag8(rn1, SELHI), B1l = mkfrag8(rn1, SELLO);
    aD00 = mf(A0h,B0h,aD00); aD00 = mf(A0h,B0l,aD00); aD00 = mf(A0l,B0h,aD00);
    aD01 = mf(A0h,B1h,aD01); aD01 = mf(A0h,B1l,aD01); aD01 = mf(A0l,B1h,aD01);
    aD10 = mf(A1h,B0h,aD10); aD10 = mf(A1h,B0l,aD10); aD10 = mf(A1l,B0h,aD10);
    aD11 = mf(A1h,B1h,aD11); aD11 = mf(A1h,B1l,aD11); aD11 = mf(A1l,B1h,aD11);
  };

  // elementwise for one 32-col half; EV yields the addresses float4 for rq.
#define ELEM(T2, ACU, ACW, EV)                                         \
    { const int sx_ = (c32 & 7) << 2;                                  \
      uint32_t* bF_ = &pF[c32*64];                                     \
      uint32_t* bN_ = &pN[c32*64];                                     \
      _Pragma("unroll")                                                \
      for (int rq = 0; rq < 4; ++rq) {                                 \
        float4 ev_ = (EV);                                             \
        uint32_t pf_[4], pn_[4];                                       \
        _Pragma("unroll")                                              \
        for (int i = 0; i < 4; ++i) {                                  \
          const int r = rq*4 + i;                                      \
          float upd = ACU[r];                                          \
          float wx  = ACW[r];                                          \
          float wp  = __builtin_amdgcn_rcpf(1.f + __expf(-wx));        \
          float mv  = F4C(M_[(T2)*4 + rq], i);                         \
          float av  = F4C(ev_, i);                                     \
          float nm  = fmaf(wp, upd - mv, mv);                          \
          float fv  = fmaxf(nm + av, 0.f);                             \
          n2a[(T2)*16 + r] += fv;                                      \
          pn_[i] = packsplit(nm);                                      \
          pf_[i] = packsplit(fv);                                      \
        }                                                              \
        const int col = (32*(T2) + 8*rq + 4*g32) ^ sx_;                \
        *(uint4*)&bF_[col] = make_uint4(pf_[0],pf_[1],pf_[2],pf_[3]);  \
        *(uint4*)&bN_[col] = make_uint4(pn_[0],pn_[1],pn_[2],pn_[3]);  \
      } }

  // ---- prologue: B(0) + M(0) ----
  f32x16 aBcur = Zv, aBnext;
  float4 M_[8];
  {
    uint4 q0[8];
    #pragma unroll
    for (int j = 0; j < 8; ++j) q0[j] = *(const uint4*)(qaBase + j*256);
    #pragma unroll
    for (int ks = 0; ks < 4; ++ks) {
      uint4 Ah_ = *(uint4*)&fkFrag[((ks*2+0)*64 + lane)*4];
      uint4 Al_ = *(uint4*)&fkFrag[((ks*2+1)*64 + lane)*4];
      aBcur = mf(Ah_, q0[ks*2+0], aBcur);
      aBcur = mf(Ah_, q0[ks*2+1], aBcur);
      aBcur = mf(Al_, q0[ks*2+0], aBcur);
    }
  }
  #pragma unroll
  for (int k = 0; k < 8; ++k) M_[k] = *(const float4*)(mRow0 + k*8 + g32*4);

  #pragma unroll 1
  for (int ss = 0; ss < 16; ++ss) {
    asm volatile("" ::: "memory");  // block LICM of loop-invariant LDS reads

    // ---- 1. finish B(ss): S, den, rden folded into S-fragment ----
    float s0 = aBcur[0], s1 = aBcur[1], s2 = aBcur[2], s3 = aBcur[3];
    float own = (s0 + s1) + (s2 + s3);
    float den = own + __shfl_xor(own, 32) + EPSF;
    float rden = __builtin_amdgcn_rcpf(den);
    float p0 = __shfl_xor(s0, 32), p1 = __shfl_xor(s1, 32),
          p2 = __shfl_xor(s2, 32), p3 = __shfl_xor(s3, 32);
    float rm = (g32 == 0) ? rden : 0.f;   // K-pad mask * rden
    uint32_t sp[8] = { packsplit(s0*rm), packsplit(s1*rm), packsplit(s2*rm), packsplit(s3*rm),
                       packsplit(p0*rm), packsplit(p1*rm), packsplit(p2*rm), packsplit(p3*rm) };
    uint4 Sh = mkfrag8(sp, SELHI), Sl = mkfrag8(sp, SELLO);

    // ---- 2. qa loads for ss+1 (one-phase live) + C-MFMAs first half ----
    uint4 qn[8];
    if (ss < 15) {
      const uint32_t* qp = qaBase + (size_t)(ss+1)*2048;
      #pragma unroll
      for (int j = 0; j < 8; ++j) qn[j] = *(const uint4*)(qp + j*256);
    }
    f32x16 aC0 = Zv, aC2 = Zv;
    {
      uint4 Vh, Vl;
      Vh = *(uint4*)&vFrag[(0*64 + lane)*4]; Vl = *(uint4*)&vFrag[(1*64 + lane)*4];
      aC0 = mf(Vh, Sh, aC0); aC0 = mf(Vh, Sl, aC0); aC0 = mf(Vl, Sh, aC0);
      Vh = *(uint4*)&vFrag[(4*64 + lane)*4]; Vl = *(uint4*)&vFrag[(5*64 + lane)*4];
      aC2 = mf(Vh, Sh, aC2); aC2 = mf(Vh, Sl, aC2); aC2 = mf(Vl, Sh, aC2);
    }

    // ---- 3. pipeline: B-MFMAs for ss+1 (qn consumed, dies here) ----
    aBnext = Zv;
    if (ss < 15) {
      #pragma unroll
      for (int ks = 0; ks < 4; ++ks) {
        uint4 Ah_ = *(uint4*)&fkFrag[((ks*2+0)*64 + lane)*4];
        uint4 Al_ = *(uint4*)&fkFrag[((ks*2+1)*64 + lane)*4];
        aBnext = mf(Ah_, qn[ks*2+0], aBnext);
        aBnext = mf(Ah_, qn[ks*2+1], aBnext);
        aBnext = mf(Al_, qn[ks*2+0], aBnext);
      }
    }

    // ---- 4. E half-1 preload (16 regs; before any M_ issue) ----
    const float* ap0 = aRow0 + (size_t)ss * 2048;
    float4 E1_[4];
    #pragma unroll
    for (int rq = 0; rq < 4; ++rq) E1_[rq] = *(const float4*)(ap0 + 32 + 8*rq + g32*4);

    // ---- 5. ELEM half 0 (E loaded inline, L1-hot, pre-M_) ----
    ELEM(0, aC0, aC2, *(const float4*)(ap0 + 8*rq + g32*4));

    // ---- 6. M_[0..3] <- ss+1 (HBM stream, stays in flight) ----
    if (ss < 15) {
      const float* mp = mRow0 + (size_t)(ss+1) * 2048;
      #pragma unroll
      for (int k = 0; k < 4; ++k) M_[k] = *(const float4*)(mp + k*8 + g32*4);
    }

    // ---- 7. C-MFMAs, second half (e-tiles 1 and 3) ----
    f32x16 aC1 = Zv, aC3 = Zv;
    {
      uint4 Vh, Vl;
      Vh = *(uint4*)&vFrag[(2*64 + lane)*4]; Vl = *(uint4*)&vFrag[(3*64 + lane)*4];
      aC1 = mf(Vh, Sh, aC1); aC1 = mf(Vh, Sl, aC1); aC1 = mf(Vl, Sh, aC1);
      Vh = *(uint4*)&vFrag[(6*64 + lane)*4]; Vl = *(uint4*)&vFrag[(7*64 + lane)*4];
      aC3 = mf(Vh, Sh, aC3); aC3 = mf(Vh, Sl, aC3); aC3 = mf(Vl, Sh, aC3);
    }

    // ---- 8. ELEM half 1 (uses E1_; no fast-load waits after M_) ----
    ELEM(1, aC1, aC3, E1_[rq]);

    // ---- 9. M_[4..7] <- ss+1 ----
    if (ss < 15) {
      const float* mp = mRow0 + (size_t)(ss+1) * 2048;
      #pragma unroll
      for (int k = 4; k < 8; ++k) M_[k] = *(const float4*)(mp + k*8 + g32*4);
    }

    // ---- 10. phase D: both 16-row chunks (DS + MFMA only) ----
    asm volatile("" ::: "memory");
    do_mfma(0);
    do_mfma(16);

    aBcur = aBnext;
  }

  // ================= epilogue =================
  __syncthreads();   // everyone done with fkFrag/vFrag/pk

  float* n2stageF = (float*)SH;            // [4][64]
  float* norm2F   = ((float*)SH) + 256;    // [64]
  float* den2F    = ((float*)SH) + 320;    // [8]
  float* stageF   = (float*)pkbase;        // [4][16][66]
  const float* fqg = proj + (size_t)b * 2048 + 1536;

  #pragma unroll
  for (int k = 0; k < 32; ++k) {
    float v = n2a[k];
    v += __shfl_xor(v, 1); v += __shfl_xor(v, 2); v += __shfl_xor(v, 4);
    v += __shfl_xor(v, 8); v += __shfl_xor(v, 16);
    n2a[k] = v;
  }
  if (c32 == 0) {
    #pragma unroll
    for (int t2 = 0; t2 < 2; ++t2)
      #pragma unroll
      for (int r = 0; r < 16; ++r) {
        const int j = 32*t2 + 8*(r>>2) + (r&3) + 4*g32;
        n2stageF[wave*64 + j] = n2a[t2*16 + r];
      }
  }
  __syncthreads();
  if (tid < 64)
    norm2F[tid] = (n2stageF[tid] + n2stageF[64+tid]) + (n2stageF[128+tid] + n2stageF[192+tid]);
  __syncthreads();
  if (tid < 8) {
    float s = 0.f;
    for (int d = 0; d < 64; ++d) s = fmaf(fqg[tid*64 + d], norm2F[d], s);
    den2F[tid] = s + EPSF;
  }

  const int hh = tid >> 5;
  const int ee = (tid & 31) * 2;
  float num2a = 0.f, num2b = 0.f;
  #pragma unroll
  for (int p = 0; p < 4; ++p) {
    const int ti = p >> 1, rh = p & 1;
    #pragma unroll
    for (int q = 0; q < 8; ++q) {
      const int rr = (q & 3) + 8*((q >> 2) & 1) + 4*g32;
      const int r = rh*8 + q;
      float v0 = (ti == 0) ? aD00[r] : aD10[r];
      float v1 = (ti == 0) ? aD01[r] : aD11[r];
      stageF[wave*1056 + rr*66 + c32]      = v0;
      stageF[wave*1056 + rr*66 + 32 + c32] = v1;
    }
    __syncthreads();
    #pragma unroll 8
    for (int dl = 0; dl < 16; ++dl) {
      float2 q0 = *(const float2*)&stageF[0*1056 + dl*66 + ee];
      float2 q1 = *(const float2*)&stageF[1*1056 + dl*66 + ee];
      float2 q2 = *(const float2*)&stageF[2*1056 + dl*66 + ee];
      float2 q3 = *(const float2*)&stageF[3*1056 + dl*66 + ee];
      float v0 = (q0.x + q1.x) + (q2.x + q3.x);
      float v1 = (q0.y + q1.y) + (q2.y + q3.y);
      float fv = fqg[hh*64 + p*16 + dl];
      num2a = fmaf(fv, v0, num2a);
      num2b = fmaf(fv, v1, num2b);
    }
    __syncthreads();
  }
  float rd2 = __builtin_amdgcn_rcpf(den2F[hh]);
  attn[(size_t)b*512 + hh*64 + ee]     = num2a * rd2;
  attn[(size_t)b*512 + hh*64 + ee + 1] = num2b * rd2;
#undef ELEM
}

// =====================================================================
// Kernel 3: out = attn(512x512) @ Wm(512x1024) + bm (unchanged)
// =====================================================================
__global__ __launch_bounds__(256) void out_gemm_kernel(
    const float* __restrict__ A, const float* __restrict__ Wm,
    const float* __restrict__ bm, float* __restrict__ out)
{
  __shared__ float As[16][68];
  __shared__ float Bs[16][68];
  const int col0 = blockIdx.x * 64;
  const int row0 = blockIdx.y * 64;
  const int tid = threadIdx.x;
  const int tr = tid >> 4, tc = tid & 15;
  float acc[4][4] = {};
  for (int k0 = 0; k0 < 512; k0 += 16) {
    {
      int r = tid >> 2, kk = (tid & 3) << 2;
      float4 a4 = *(const float4*)&A[(size_t)(row0 + r) * 512 + k0 + kk];
      As[kk+0][r] = a4.x; As[kk+1][r] = a4.y; As[kk+2][r] = a4.z; As[kk+3][r] = a4.w;
    }
    {
      int kr = tid >> 4, cc = (tid & 15) << 2;
      *(float4*)&Bs[kr][cc] = *(const float4*)&Wm[(size_t)(k0 + kr) * 1024 + col0 + cc];
    }
    __syncthreads();
    #pragma unroll
    for (int k = 0; k < 16; ++k) {
      float4 av4 = *(const float4*)&As[k][tr*4];
      float4 bv4 = *(const float4*)&Bs[k][tc*4];
      float av[4] = {av4.x, av4.y, av4.z, av4.w};
      float bb[4] = {bv4.x, bv4.y, bv4.z, bv4.w};
      #pragma unroll
      for (int i = 0; i < 4; ++i)
        #pragma unroll
        for (int j = 0; j < 4; ++j)
          acc[i][j] = fmaf(av[i], bb[j], acc[i][j]);
    }
    __syncthreads();
  }
  #pragma unroll
  for (int i = 0; i < 4; ++i) {
    int r = row0 + tr*4 + i;
    #pragma unroll
    for (int j = 0; j < 4; ++j) {
      int c = col0 + tc*4 + j;
      out[(size_t)r * 1024 + c] = acc[i][j] + bm[c];
    }
  }
}

extern "C" void kernel_launch(void* const* d_in, const int* in_sizes, int n_in,
                              void* d_out, int out_size, void* d_ws, size_t ws_size,
                              hipStream_t stream)
{
  const float* x    = (const float*)d_in[0];
  const float* mem  = (const float*)d_in[1];
  const float* addr = (const float*)d_in[2];
  const float* Wk   = (const float*)d_in[3];
  const float* bk   = (const float*)d_in[4];
  const float* Wv   = (const float*)d_in[5];
  const float* bv   = (const float*)d_in[6];
  const float* Wq   = (const float*)d_in[7];
  const float* bq   = (const float*)d_in[8];
  const float* Wm   = (const float*)d_in[9];
  const float* bm   = (const float*)d_in[10];
  float* out  = (float*)d_out;
  float* ws   = (float*)d_ws;
  float* proj = ws;                          // 512*2048 floats (4 MB)
  float* attn = ws + (size_t)512 * 2048;     // 512*512 floats (1 MB)
  uint32_t* qaF = (uint32_t*)(ws + (size_t)512 * 2048 + (size_t)512 * 512);  // 512 KB

  hipLaunchKernelGGL(qa_pack_kernel, dim3(64), dim3(64), 0, stream,
                     addr, qaF);
  hipLaunchKernelGGL(proj_gemm_kernel, dim3(32, 8), dim3(256), 0, stream,
                     x, Wk, bk, Wv, bv, Wq, bq, proj);
  hipLaunchKernelGGL(fused_mem_kernel, dim3(512), dim3(256), 0, stream,
                     mem, addr, proj, qaF, attn);
  hipLaunchKernelGGL(out_gemm_kernel, dim3(16, 8), dim3(256), 0, stream,
                     attn, Wm, bm, out);
}

// Round 11
// 212.297 us; speedup vs baseline: 1.1679x; 1.1679x over previous
//
#include <hip/hip_runtime.h>
#include <hip/hip_bf16.h>
#include <math.h>

#define EPSF 1e-5f
#define SELHI 0x05040100u
#define SELLO 0x07060302u

typedef __attribute__((ext_vector_type(8))) short bf16x8;
typedef __attribute__((ext_vector_type(16))) float f32x16;

// pack float -> u32 { low16 = hi-bf16 (truncated), high16 = lo-bf16 (residual) }
__device__ __forceinline__ uint32_t packsplit(float x) {
  uint32_t xb = __builtin_bit_cast(uint32_t, x);
  float hi = __builtin_bit_cast(float, xb & 0xFFFF0000u);
  float resid = x - hi;
  return __builtin_amdgcn_perm(__builtin_bit_cast(uint32_t, resid), xb, 0x07060302u);
}

// 8 packed u32 -> one 8xbf16 fragment (SELHI = hi halves, SELLO = residuals)
__device__ __forceinline__ uint4 mkfrag8(const uint32_t* p, uint32_t sel) {
  uint4 u;
  u.x = __builtin_amdgcn_perm(p[1], p[0], sel);
  u.y = __builtin_amdgcn_perm(p[3], p[2], sel);
  u.z = __builtin_amdgcn_perm(p[5], p[4], sel);
  u.w = __builtin_amdgcn_perm(p[7], p[6], sel);
  return u;
}

__device__ __forceinline__ f32x16 mf(uint4 a, uint4 b, f32x16 c) {
  return __builtin_amdgcn_mfma_f32_32x32x16_bf16(
      __builtin_bit_cast(bf16x8, a), __builtin_bit_cast(bf16x8, b), c, 0, 0, 0);
}

#define F4C(v, i) ((i) == 0 ? (v).x : (i) == 1 ? (v).y : (i) == 2 ? (v).z : (v).w)

// =====================================================================
// Kernel 0: qa fragment precompute (batch-independent addresses ->
//   MFMA B-fragment table, 512 KB, built once).
// =====================================================================
__global__ __launch_bounds__(64) void qa_pack_kernel(
    const float* __restrict__ addresses, uint32_t* __restrict__ qaF)
{
  const int T = blockIdx.x;
  const int lane = threadIdx.x;
  const int g32 = lane >> 5, c32 = lane & 31;
  #pragma unroll
  for (int ks = 0; ks < 4; ++ks) {
    const float* ap = addresses + (size_t)(T*32 + c32)*64 + ks*16 + g32*8;
    float4 f0 = *(const float4*)ap;
    float4 f1 = *(const float4*)(ap + 4);
    uint32_t qp[8] = {
      packsplit(fmaxf(f0.x,0.f)), packsplit(fmaxf(f0.y,0.f)),
      packsplit(fmaxf(f0.z,0.f)), packsplit(fmaxf(f0.w,0.f)),
      packsplit(fmaxf(f1.x,0.f)), packsplit(fmaxf(f1.y,0.f)),
      packsplit(fmaxf(f1.z,0.f)), packsplit(fmaxf(f1.w,0.f)) };
    *(uint4*)&qaF[(size_t)T*2048 + (ks*2+0)*256 + lane*4] = mkfrag8(qp, SELHI);
    *(uint4*)&qaF[(size_t)T*2048 + (ks*2+1)*256 + lane*4] = mkfrag8(qp, SELLO);
  }
}

// =====================================================================
// Kernel 1: fused projection GEMM (unchanged)
// =====================================================================
__global__ __launch_bounds__(256) void proj_gemm_kernel(
    const float* __restrict__ x,
    const float* __restrict__ Wk, const float* __restrict__ bk,
    const float* __restrict__ Wv, const float* __restrict__ bv,
    const float* __restrict__ Wq, const float* __restrict__ bq,
    float* __restrict__ proj)
{
  __shared__ float As[16][68];
  __shared__ float Bs[16][68];
  const int col0 = blockIdx.x * 64;
  const int row0 = blockIdx.y * 64;
  const float* Bp; const float* bias; int ldb, bcol, relu;
  if (col0 < 512)       { Bp = Wk; bias = bk; ldb = 512;  bcol = col0;        relu = 1; }
  else if (col0 < 1536) { Bp = Wv; bias = bv; ldb = 1024; bcol = col0 - 512;  relu = 0; }
  else                  { Bp = Wq; bias = bq; ldb = 512;  bcol = col0 - 1536; relu = 1; }
  const int tid = threadIdx.x;
  const int tr = tid >> 4, tc = tid & 15;
  float acc[4][4] = {};
  for (int k0 = 0; k0 < 1024; k0 += 16) {
    {
      int r = tid >> 2, kk = (tid & 3) << 2;
      float4 a4 = *(const float4*)&x[(size_t)(row0 + r) * 1024 + k0 + kk];
      As[kk+0][r] = a4.x; As[kk+1][r] = a4.y; As[kk+2][r] = a4.z; As[kk+3][r] = a4.w;
    }
    {
      int kr = tid >> 4, cc = (tid & 15) << 2;
      *(float4*)&Bs[kr][cc] = *(const float4*)&Bp[(size_t)(k0 + kr) * ldb + bcol + cc];
    }
    __syncthreads();
    #pragma unroll
    for (int k = 0; k < 16; ++k) {
      float4 av4 = *(const float4*)&As[k][tr*4];
      float4 bv4 = *(const float4*)&Bs[k][tc*4];
      float av[4] = {av4.x, av4.y, av4.z, av4.w};
      float bb[4] = {bv4.x, bv4.y, bv4.z, bv4.w};
      #pragma unroll
      for (int i = 0; i < 4; ++i)
        #pragma unroll
        for (int j = 0; j < 4; ++j)
          acc[i][j] = fmaf(av[i], bb[j], acc[i][j]);
    }
    __syncthreads();
  }
  #pragma unroll
  for (int i = 0; i < 4; ++i) {
    int r = row0 + tr*4 + i;
    #pragma unroll
    for (int j = 0; j < 4; ++j) {
      int cl = tc*4 + j;
      float v = acc[i][j] + bias[bcol + cl];
      if (relu) v = fmaxf(v, 0.f);
      proj[(size_t)r * 2048 + col0 + cl] = v;
    }
  }
}

// =====================================================================
// Kernel 2: fused memory kernel, R10 = R6 structure (163us, no spill)
//   + zero-register-cost VALU cuts only:
//   - sigmoid/rden via v_rcp_f32 (1 ulp)
//   - qaF table loads interleaved PER-KS (8 regs live, like R6's temps)
//   - rden folded into S-fragment pack
//   Nothing else moved: R8/R9 proved any >=16-reg cross-phase addition
//   spills (unified VGPR+AGPR file at the 256/wave cap).
// =====================================================================
__global__ __launch_bounds__(256, 2) void fused_mem_kernel(
    const float* __restrict__ memories,   // [512][2048][64]
    const float* __restrict__ addresses,  // [2048][64]
    const float* __restrict__ proj,       // [512][2048] = fk|v|fq
    const uint32_t* __restrict__ qaF,     // [64][8][64][4] qa fragments
    float* __restrict__ attn)             // [512][512]
{
  // 80 KB arena:
  //  [0,2048)      fkFrag   (epilogue: n2stage/norm2/den2 overlay)
  //  [2048,4096)   vFrag
  //  [4096,20480)  pk region: 4 waves x { pF[32][64], pN[32][64] }
  __shared__ uint32_t SH[20480];

  const int b = blockIdx.x, tid = threadIdx.x;
  const int wave = tid >> 6, lane = tid & 63;
  const int g32 = lane >> 5, c32 = lane & 31;

  uint32_t* fkFrag = SH;
  uint32_t* vFrag  = SH + 2048;
  uint32_t* pkbase = SH + 4096;
  uint32_t* pF = pkbase + wave * 4096;   // [32][64] u32, col ^= (row&7)<<2
  uint32_t* pN = pF + 2048;

  // ---- stage proj row (pbuf overlays pk region) ----
  float* pbuf = (float*)pkbase;
  {
    const float* prow = proj + (size_t)b * 2048;
    *(float4*)&pbuf[tid*8]   = *(const float4*)&prow[tid*8];
    *(float4*)&pbuf[tid*8+4] = *(const float4*)&prow[tid*8+4];
  }
  __syncthreads();

  // ---- one-time fragment packing (wave w: kstep w, e-tile w) ----
  {
    const int ks = wave;
    float4 f0 = *(const float4*)&pbuf[c32*64 + ks*16 + g32*8];
    float4 f1 = *(const float4*)&pbuf[c32*64 + ks*16 + g32*8 + 4];
    uint32_t p[8] = { packsplit(f0.x), packsplit(f0.y), packsplit(f0.z), packsplit(f0.w),
                      packsplit(f1.x), packsplit(f1.y), packsplit(f1.z), packsplit(f1.w) };
    *(uint4*)&fkFrag[((ks*2+0)*64 + lane)*4] = mkfrag8(p, SELHI);
    *(uint4*)&fkFrag[((ks*2+1)*64 + lane)*4] = mkfrag8(p, SELLO);
    const int t = wave;
    uint32_t q[8];
    #pragma unroll
    for (int j = 0; j < 8; ++j) {
      int h = (g32*8 + j) & 7;
      q[j] = packsplit(pbuf[512 + h*128 + t*32 + c32]);
    }
    *(uint4*)&vFrag[((t*2+0)*64 + lane)*4] = mkfrag8(q, SELHI);
    *(uint4*)&vFrag[((t*2+1)*64 + lane)*4] = mkfrag8(q, SELLO);
  }
  __syncthreads();

  f32x16 Zv;
  #pragma unroll
  for (int r = 0; r < 16; ++r) Zv[r] = 0.f;
  f32x16 aD00 = Zv, aD01 = Zv, aD10 = Zv, aD11 = Zv;
  float n2a[32];
  #pragma unroll
  for (int k = 0; k < 32; ++k) n2a[k] = 0.f;

  const float* aRow0 = addresses + (size_t)(wave*512 + c32) * 64;
  const float* mRow0 = memories + ((size_t)b*2048 + wave*512 + c32) * 64;
  const uint32_t* qaBase = qaF + (size_t)(wave*16)*2048 + lane*4;

  auto do_mfma = [&](int base) {
    uint32_t rf0[8], rf1[8], rn0[8], rn1[8];
    #pragma unroll
    for (int e = 0; e < 8; ++e) {
      const int row = base + g32*8 + e;
      const int cs = c32 ^ ((row & 7) << 2);
      rf0[e] = pF[row*64 + cs];
      rf1[e] = pF[row*64 + 32 + cs];
      rn0[e] = pN[row*64 + cs];
      rn1[e] = pN[row*64 + 32 + cs];
    }
    uint4 A0h = mkfrag8(rf0, SELHI), A0l = mkfrag8(rf0, SELLO);
    uint4 A1h = mkfrag8(rf1, SELHI), A1l = mkfrag8(rf1, SELLO);
    uint4 B0h = mkfrag8(rn0, SELHI), B0l = mkfrag8(rn0, SELLO);
    uint4 B1h = mkfrag8(rn1, SELHI), B1l = mkfrag8(rn1, SELLO);
    aD00 = mf(A0h,B0h,aD00); aD00 = mf(A0h,B0l,aD00); aD00 = mf(A0l,B0h,aD00);
    aD01 = mf(A0h,B1h,aD01); aD01 = mf(A0h,B1l,aD01); aD01 = mf(A0l,B1h,aD01);
    aD10 = mf(A1h,B0h,aD10); aD10 = mf(A1h,B0l,aD10); aD10 = mf(A1l,B0h,aD10);
    aD11 = mf(A1h,B1h,aD11); aD11 = mf(A1h,B1l,aD11); aD11 = mf(A1l,B1h,aD11);
  };

  // B-MFMAs from the qa table: loads interleaved per-ks (8 regs live).
#define QATAB_B(QP, ACC) do {                                          \
    _Pragma("unroll")                                                  \
    for (int ks = 0; ks < 4; ++ks) {                                   \
      uint4 qh_ = *(const uint4*)((QP) + (ks*2+0)*256);                \
      uint4 ql_ = *(const uint4*)((QP) + (ks*2+1)*256);                \
      uint4 Ah_ = *(uint4*)&fkFrag[((ks*2+0)*64 + lane)*4];            \
      uint4 Al_ = *(uint4*)&fkFrag[((ks*2+1)*64 + lane)*4];            \
      ACC = mf(Ah_, qh_, ACC); ACC = mf(Ah_, ql_, ACC); ACC = mf(Al_, qh_, ACC); \
    } } while(0)

  // elementwise for one 32-col half; aC already carries num*rden
  // (rden folded into S pack). Sigmoid via v_rcp. Lazy E loads (8 regs);
  // packs 4 values, b128-writes straight to the per-wave pk tile.
#define ELEM(T2, ACU, ACW) do {                                        \
    const int sx_ = (c32 & 7) << 2;                                    \
    uint32_t* bF_ = &pF[c32*64];                                       \
    uint32_t* bN_ = &pN[c32*64];                                       \
    _Pragma("unroll")                                                  \
    for (int rq = 0; rq < 4; ++rq) {                                   \
      uint32_t pf_[4], pn_[4];                                         \
      _Pragma("unroll")                                                \
      for (int i = 0; i < 4; ++i) {                                    \
        const int r = rq*4 + i;                                        \
        float upd = ACU[r];                                            \
        float wx  = ACW[r];                                            \
        float wp  = __builtin_amdgcn_rcpf(1.f + __expf(-wx));          \
        float mv  = F4C(M_[(T2)*4 + rq], i);                           \
        float av  = F4C(E_[rq & 1], i);                                \
        float nm  = fmaf(wp, upd - mv, mv);                            \
        float fv  = fmaxf(nm + av, 0.f);                               \
        n2a[(T2)*16 + r] += fv;                                        \
        pn_[i] = packsplit(nm);                                        \
        pf_[i] = packsplit(fv);                                        \
      }                                                                \
      if (rq == 1) { E_[0] = *(const float4*)(ap0 + (T2)*32 + 16 + g32*4);      \
                     E_[1] = *(const float4*)(ap0 + (T2)*32 + 16 + g32*4 + 8); }\
      const int col = (32*(T2) + 8*rq + 4*g32) ^ sx_;                  \
      *(uint4*)&bF_[col] = make_uint4(pf_[0],pf_[1],pf_[2],pf_[3]);    \
      *(uint4*)&bN_[col] = make_uint4(pn_[0],pn_[1],pn_[2],pn_[3]);    \
    } } while(0)

  // ---- prologue: B(0) + M(0) ----
  f32x16 aBcur = Zv, aBnext;
  float4 M_[8];
  QATAB_B(qaBase, aBcur);
  #pragma unroll
  for (int k = 0; k < 8; ++k) M_[k] = *(const float4*)(mRow0 + k*8 + g32*4);

  #pragma unroll 1
  for (int ss = 0; ss < 16; ++ss) {
    asm volatile("" ::: "memory");  // block LICM of loop-invariant LDS reads

    // ---- 1. finish B(ss): S, den; rden folded into S-fragment ----
    float s0 = aBcur[0], s1 = aBcur[1], s2 = aBcur[2], s3 = aBcur[3];
    float own = (s0 + s1) + (s2 + s3);
    float den = own + __shfl_xor(own, 32) + EPSF;
    float rden = __builtin_amdgcn_rcpf(den);
    float p0 = __shfl_xor(s0, 32), p1 = __shfl_xor(s1, 32),
          p2 = __shfl_xor(s2, 32), p3 = __shfl_xor(s3, 32);
    float rm = (g32 == 0) ? rden : 0.f;   // K-pad mask * rden
    uint32_t sp[8] = { packsplit(s0*rm), packsplit(s1*rm), packsplit(s2*rm), packsplit(s3*rm),
                       packsplit(p0*rm), packsplit(p1*rm), packsplit(p2*rm), packsplit(p3*rm) };
    uint4 Sh = mkfrag8(sp, SELHI), Sl = mkfrag8(sp, SELLO);

    // ---- 2. C-MFMAs, first half (e-tiles 0 and 2) ----
    f32x16 aC0 = Zv, aC2 = Zv;
    {
      uint4 Vh, Vl;
      Vh = *(uint4*)&vFrag[(0*64 + lane)*4]; Vl = *(uint4*)&vFrag[(1*64 + lane)*4];
      aC0 = mf(Vh, Sh, aC0); aC0 = mf(Vh, Sl, aC0); aC0 = mf(Vl, Sh, aC0);
      Vh = *(uint4*)&vFrag[(4*64 + lane)*4]; Vl = *(uint4*)&vFrag[(5*64 + lane)*4];
      aC2 = mf(Vh, Sh, aC2); aC2 = mf(Vh, Sl, aC2); aC2 = mf(Vl, Sh, aC2);
    }

    // ---- 3. pipeline: B-MFMAs for ss+1 (per-ks interleaved loads) ----
    aBnext = Zv;
    if (ss < 15) {
      const uint32_t* qp = qaBase + (size_t)(ss+1)*2048;
      QATAB_B(qp, aBnext);
    }

    // ---- 4. ELEM half 0 (lazy E loads, L1-hot) ----
    const float* ap0 = aRow0 + (size_t)ss * 2048;
    float4 E_[2];
    E_[0] = *(const float4*)(ap0 + g32*4);
    E_[1] = *(const float4*)(ap0 + g32*4 + 8);
    ELEM(0, aC0, aC2);

    // ---- 5. C-MFMAs, second half (e-tiles 1 and 3) ----
    f32x16 aC1 = Zv, aC3 = Zv;
    {
      uint4 Vh, Vl;
      Vh = *(uint4*)&vFrag[(2*64 + lane)*4]; Vl = *(uint4*)&vFrag[(3*64 + lane)*4];
      aC1 = mf(Vh, Sh, aC1); aC1 = mf(Vh, Sl, aC1); aC1 = mf(Vl, Sh, aC1);
      Vh = *(uint4*)&vFrag[(6*64 + lane)*4]; Vl = *(uint4*)&vFrag[(7*64 + lane)*4];
      aC3 = mf(Vh, Sh, aC3); aC3 = mf(Vh, Sl, aC3); aC3 = mf(Vl, Sh, aC3);
    }

    // ---- 6. M_[0..3] <- ss+1 (HBM stream) ----
    if (ss < 15) {
      const float* mp = mRow0 + (size_t)(ss+1) * 2048;
      #pragma unroll
      for (int k = 0; k < 4; ++k) M_[k] = *(const float4*)(mp + k*8 + g32*4);
    }

    // ---- 7. ELEM half 1 ----
    E_[0] = *(const float4*)(ap0 + 32 + g32*4);
    E_[1] = *(const float4*)(ap0 + 32 + g32*4 + 8);
    ELEM(1, aC1, aC3);

    // ---- 8. M_[4..7] <- ss+1 ----
    if (ss < 15) {
      const float* mp = mRow0 + (size_t)(ss+1) * 2048;
      #pragma unroll
      for (int k = 4; k < 8; ++k) M_[k] = *(const float4*)(mp + k*8 + g32*4);
    }

    // ---- 9. phase D: both 16-row chunks (DS + MFMA only) ----
    asm volatile("" ::: "memory");
    do_mfma(0);
    do_mfma(16);

    aBcur = aBnext;
  }

  // ================= epilogue =================
  __syncthreads();   // everyone done with fkFrag/vFrag/pk

  float* n2stageF = (float*)SH;            // [4][64]
  float* norm2F   = ((float*)SH) + 256;    // [64]
  float* den2F    = ((float*)SH) + 320;    // [8]
  float* stageF   = (float*)pkbase;        // [4][16][66]
  const float* fqg = proj + (size_t)b * 2048 + 1536;

  #pragma unroll
  for (int k = 0; k < 32; ++k) {
    float v = n2a[k];
    v += __shfl_xor(v, 1); v += __shfl_xor(v, 2); v += __shfl_xor(v, 4);
    v += __shfl_xor(v, 8); v += __shfl_xor(v, 16);
    n2a[k] = v;
  }
  if (c32 == 0) {
    #pragma unroll
    for (int t2 = 0; t2 < 2; ++t2)
      #pragma unroll
      for (int r = 0; r < 16; ++r) {
        const int j = 32*t2 + 8*(r>>2) + (r&3) + 4*g32;
        n2stageF[wave*64 + j] = n2a[t2*16 + r];
      }
  }
  __syncthreads();
  if (tid < 64)
    norm2F[tid] = (n2stageF[tid] + n2stageF[64+tid]) + (n2stageF[128+tid] + n2stageF[192+tid]);
  __syncthreads();
  if (tid < 8) {
    float s = 0.f;
    for (int d = 0; d < 64; ++d) s = fmaf(fqg[tid*64 + d], norm2F[d], s);
    den2F[tid] = s + EPSF;
  }

  const int hh = tid >> 5;
  const int ee = (tid & 31) * 2;
  float num2a = 0.f, num2b = 0.f;
  #pragma unroll
  for (int p = 0; p < 4; ++p) {
    const int ti = p >> 1, rh = p & 1;
    #pragma unroll
    for (int q = 0; q < 8; ++q) {
      const int rr = (q & 3) + 8*((q >> 2) & 1) + 4*g32;
      const int r = rh*8 + q;
      float v0 = (ti == 0) ? aD00[r] : aD10[r];
      float v1 = (ti == 0) ? aD01[r] : aD11[r];
      stageF[wave*1056 + rr*66 + c32]      = v0;
      stageF[wave*1056 + rr*66 + 32 + c32] = v1;
    }
    __syncthreads();
    #pragma unroll 8
    for (int dl = 0; dl < 16; ++dl) {
      float2 q0 = *(const float2*)&stageF[0*1056 + dl*66 + ee];
      float2 q1 = *(const float2*)&stageF[1*1056 + dl*66 + ee];
      float2 q2 = *(const float2*)&stageF[2*1056 + dl*66 + ee];
      float2 q3 = *(const float2*)&stageF[3*1056 + dl*66 + ee];
      float v0 = (q0.x + q1.x) + (q2.x + q3.x);
      float v1 = (q0.y + q1.y) + (q2.y + q3.y);
      float fv = fqg[hh*64 + p*16 + dl];
      num2a = fmaf(fv, v0, num2a);
      num2b = fmaf(fv, v1, num2b);
    }
    __syncthreads();
  }
  float rd2 = __builtin_amdgcn_rcpf(den2F[hh]);
  attn[(size_t)b*512 + hh*64 + ee]     = num2a * rd2;
  attn[(size_t)b*512 + hh*64 + ee + 1] = num2b * rd2;
#undef ELEM
#undef QATAB_B
}

// =====================================================================
// Kernel 3: out = attn(512x512) @ Wm(512x1024) + bm (unchanged)
// =====================================================================
__global__ __launch_bounds__(256) void out_gemm_kernel(
    const float* __restrict__ A, const float* __restrict__ Wm,
    const float* __restrict__ bm, float* __restrict__ out)
{
  __shared__ float As[16][68];
  __shared__ float Bs[16][68];
  const int col0 = blockIdx.x * 64;
  const int row0 = blockIdx.y * 64;
  const int tid = threadIdx.x;
  const int tr = tid >> 4, tc = tid & 15;
  float acc[4][4] = {};
  for (int k0 = 0; k0 < 512; k0 += 16) {
    {
      int r = tid >> 2, kk = (tid & 3) << 2;
      float4 a4 = *(const float4*)&A[(size_t)(row0 + r) * 512 + k0 + kk];
      As[kk+0][r] = a4.x; As[kk+1][r] = a4.y; As[kk+2][r] = a4.z; As[kk+3][r] = a4.w;
    }
    {
      int kr = tid >> 4, cc = (tid & 15) << 2;
      *(float4*)&Bs[kr][cc] = *(const float4*)&Wm[(size_t)(k0 + kr) * 1024 + col0 + cc];
    }
    __syncthreads();
    #pragma unroll
    for (int k = 0; k < 16; ++k) {
      float4 av4 = *(const float4*)&As[k][tr*4];
      float4 bv4 = *(const float4*)&Bs[k][tc*4];
      float av[4] = {av4.x, av4.y, av4.z, av4.w};
      float bb[4] = {bv4.x, bv4.y, bv4.z, bv4.w};
      #pragma unroll
      for (int i = 0; i < 4; ++i)
        #pragma unroll
        for (int j = 0; j < 4; ++j)
          acc[i][j] = fmaf(av[i], bb[j], acc[i][j]);
    }
    __syncthreads();
  }
  #pragma unroll
  for (int i = 0; i < 4; ++i) {
    int r = row0 + tr*4 + i;
    #pragma unroll
    for (int j = 0; j < 4; ++j) {
      int c = col0 + tc*4 + j;
      out[(size_t)r * 1024 + c] = acc[i][j] + bm[c];
    }
  }
}

extern "C" void kernel_launch(void* const* d_in, const int* in_sizes, int n_in,
                              void* d_out, int out_size, void* d_ws, size_t ws_size,
                              hipStream_t stream)
{
  const float* x    = (const float*)d_in[0];
  const float* mem  = (const float*)d_in[1];
  const float* addr = (const float*)d_in[2];
  const float* Wk   = (const float*)d_in[3];
  const float* bk   = (const float*)d_in[4];
  const float* Wv   = (const float*)d_in[5];
  const float* bv   = (const float*)d_in[6];
  const float* Wq   = (const float*)d_in[7];
  const float* bq   = (const float*)d_in[8];
  const float* Wm   = (const float*)d_in[9];
  const float* bm   = (const float*)d_in[10];
  float* out  = (float*)d_out;
  float* ws   = (float*)d_ws;
  float* proj = ws;                          // 512*2048 floats (4 MB)
  float* attn = ws + (size_t)512 * 2048;     // 512*512 floats (1 MB)
  uint32_t* qaF = (uint32_t*)(ws + (size_t)512 * 2048 + (size_t)512 * 512);  // 512 KB

  hipLaunchKernelGGL(qa_pack_kernel, dim3(64), dim3(64), 0, stream,
                     addr, qaF);
  hipLaunchKernelGGL(proj_gemm_kernel, dim3(32, 8), dim3(256), 0, stream,
                     x, Wk, bk, Wv, bv, Wq, bq, proj);
  hipLaunchKernelGGL(fused_mem_kernel, dim3(512), dim3(256), 0, stream,
                     mem, addr, proj, qaF, attn);
  hipLaunchKernelGGL(out_gemm_kernel, dim3(16, 8), dim3(256), 0, stream,
                     attn, Wm, bm, out);
}

// Round 12
// 206.541 us; speedup vs baseline: 1.2004x; 1.0279x over previous
//
#include <hip/hip_runtime.h>
#include <hip/hip_bf16.h>
#include <math.h>

#define EPSF 1e-5f
#define SELHI 0x05040100u
#define SELLO 0x07060302u

typedef __attribute__((ext_vector_type(8))) short bf16x8;
typedef __attribute__((ext_vector_type(16))) float f32x16;

// pack float -> u32 { low16 = hi-bf16 (truncated), high16 = lo-bf16 (residual) }
__device__ __forceinline__ uint32_t packsplit(float x) {
  uint32_t xb = __builtin_bit_cast(uint32_t, x);
  float hi = __builtin_bit_cast(float, xb & 0xFFFF0000u);
  float resid = x - hi;
  return __builtin_amdgcn_perm(__builtin_bit_cast(uint32_t, resid), xb, 0x07060302u);
}

// float -> bf16 with round-to-nearest-even (returns 16-bit value in low bits)
__device__ __forceinline__ uint32_t bf16rne(float x) {
  uint32_t xb = __builtin_bit_cast(uint32_t, x);
  return (xb + 0x7FFFu + ((xb >> 16) & 1u)) >> 16;
}

// 8 packed u32 -> one 8xbf16 fragment (SELHI = hi halves, SELLO = residuals)
__device__ __forceinline__ uint4 mkfrag8(const uint32_t* p, uint32_t sel) {
  uint4 u;
  u.x = __builtin_amdgcn_perm(p[1], p[0], sel);
  u.y = __builtin_amdgcn_perm(p[3], p[2], sel);
  u.z = __builtin_amdgcn_perm(p[5], p[4], sel);
  u.w = __builtin_amdgcn_perm(p[7], p[6], sel);
  return u;
}

__device__ __forceinline__ f32x16 mf(uint4 a, uint4 b, f32x16 c) {
  return __builtin_amdgcn_mfma_f32_32x32x16_bf16(
      __builtin_bit_cast(bf16x8, a), __builtin_bit_cast(bf16x8, b), c, 0, 0, 0);
}

#define F4C(v, i) ((i) == 0 ? (v).x : (i) == 1 ? (v).y : (i) == 2 ? (v).z : (v).w)

// =====================================================================
// Kernel 0: qa fragment precompute (batch-independent addresses ->
//   MFMA B-fragment table, 512 KB, built once).
// =====================================================================
__global__ __launch_bounds__(64) void qa_pack_kernel(
    const float* __restrict__ addresses, uint32_t* __restrict__ qaF)
{
  const int T = blockIdx.x;
  const int lane = threadIdx.x;
  const int g32 = lane >> 5, c32 = lane & 31;
  #pragma unroll
  for (int ks = 0; ks < 4; ++ks) {
    const float* ap = addresses + (size_t)(T*32 + c32)*64 + ks*16 + g32*8;
    float4 f0 = *(const float4*)ap;
    float4 f1 = *(const float4*)(ap + 4);
    uint32_t qp[8] = {
      packsplit(fmaxf(f0.x,0.f)), packsplit(fmaxf(f0.y,0.f)),
      packsplit(fmaxf(f0.z,0.f)), packsplit(fmaxf(f0.w,0.f)),
      packsplit(fmaxf(f1.x,0.f)), packsplit(fmaxf(f1.y,0.f)),
      packsplit(fmaxf(f1.z,0.f)), packsplit(fmaxf(f1.w,0.f)) };
    *(uint4*)&qaF[(size_t)T*2048 + (ks*2+0)*256 + lane*4] = mkfrag8(qp, SELHI);
    *(uint4*)&qaF[(size_t)T*2048 + (ks*2+1)*256 + lane*4] = mkfrag8(qp, SELLO);
  }
}

// =====================================================================
// Kernel 1: fused projection GEMM (unchanged)
// =====================================================================
__global__ __launch_bounds__(256) void proj_gemm_kernel(
    const float* __restrict__ x,
    const float* __restrict__ Wk, const float* __restrict__ bk,
    const float* __restrict__ Wv, const float* __restrict__ bv,
    const float* __restrict__ Wq, const float* __restrict__ bq,
    float* __restrict__ proj)
{
  __shared__ float As[16][68];
  __shared__ float Bs[16][68];
  const int col0 = blockIdx.x * 64;
  const int row0 = blockIdx.y * 64;
  const float* Bp; const float* bias; int ldb, bcol, relu;
  if (col0 < 512)       { Bp = Wk; bias = bk; ldb = 512;  bcol = col0;        relu = 1; }
  else if (col0 < 1536) { Bp = Wv; bias = bv; ldb = 1024; bcol = col0 - 512;  relu = 0; }
  else                  { Bp = Wq; bias = bq; ldb = 512;  bcol = col0 - 1536; relu = 1; }
  const int tid = threadIdx.x;
  const int tr = tid >> 4, tc = tid & 15;
  float acc[4][4] = {};
  for (int k0 = 0; k0 < 1024; k0 += 16) {
    {
      int r = tid >> 2, kk = (tid & 3) << 2;
      float4 a4 = *(const float4*)&x[(size_t)(row0 + r) * 1024 + k0 + kk];
      As[kk+0][r] = a4.x; As[kk+1][r] = a4.y; As[kk+2][r] = a4.z; As[kk+3][r] = a4.w;
    }
    {
      int kr = tid >> 4, cc = (tid & 15) << 2;
      *(float4*)&Bs[kr][cc] = *(const float4*)&Bp[(size_t)(k0 + kr) * ldb + bcol + cc];
    }
    __syncthreads();
    #pragma unroll
    for (int k = 0; k < 16; ++k) {
      float4 av4 = *(const float4*)&As[k][tr*4];
      float4 bv4 = *(const float4*)&Bs[k][tc*4];
      float av[4] = {av4.x, av4.y, av4.z, av4.w};
      float bb[4] = {bv4.x, bv4.y, bv4.z, bv4.w};
      #pragma unroll
      for (int i = 0; i < 4; ++i)
        #pragma unroll
        for (int j = 0; j < 4; ++j)
          acc[i][j] = fmaf(av[i], bb[j], acc[i][j]);
    }
    __syncthreads();
  }
  #pragma unroll
  for (int i = 0; i < 4; ++i) {
    int r = row0 + tr*4 + i;
    #pragma unroll
    for (int j = 0; j < 4; ++j) {
      int cl = tc*4 + j;
      float v = acc[i][j] + bias[bcol + cl];
      if (relu) v = fmaxf(v, 0.f);
      proj[(size_t)r * 2048 + col0 + cl] = v;
    }
  }
}

// =====================================================================
// Kernel 2: fused memory kernel, R11 = R10 + phase-D pk tables in
//   single RNE bf16 (ushort [32][68], stride-68 -> 8B-aligned b64
//   writes bank-clean, u16 reads conflict-free across both g32 groups).
//   LDS 80 -> 51.2 KB; phase-D MFMAs 24 -> 8 per superstep; perms cut.
//   Phases B/C keep full split precision (unchanged).
// =====================================================================
__global__ __launch_bounds__(256, 2) void fused_mem_kernel(
    const float* __restrict__ memories,   // [512][2048][64]
    const float* __restrict__ addresses,  // [2048][64]
    const float* __restrict__ proj,       // [512][2048] = fk|v|fq
    const uint32_t* __restrict__ qaF,     // [64][8][64][4] qa fragments
    float* __restrict__ attn)             // [512][512]
{
  // 51.2 KB arena:
  //  [0,2048)      fkFrag   (epilogue: n2stage/norm2/den2 overlay)
  //  [2048,4096)   vFrag
  //  [4096,12800)  pk region: 4 waves x { pF16[32][68], pN16[32][68] } ushort
  //                (pbuf staging at start, stageF in epilogue)
  __shared__ uint32_t SH[12800];

  const int b = blockIdx.x, tid = threadIdx.x;
  const int wave = tid >> 6, lane = tid & 63;
  const int g32 = lane >> 5, c32 = lane & 31;

  uint32_t* fkFrag = SH;
  uint32_t* vFrag  = SH + 2048;
  uint32_t* pkbase = SH + 4096;
  unsigned short* pF16 = (unsigned short*)(pkbase + wave * 2176);  // [32][68]
  unsigned short* pN16 = pF16 + 2176;                              // 32*68

  // ---- stage proj row (pbuf overlays pk region) ----
  float* pbuf = (float*)pkbase;
  {
    const float* prow = proj + (size_t)b * 2048;
    *(float4*)&pbuf[tid*8]   = *(const float4*)&prow[tid*8];
    *(float4*)&pbuf[tid*8+4] = *(const float4*)&prow[tid*8+4];
  }
  __syncthreads();

  // ---- one-time fragment packing (wave w: kstep w, e-tile w) ----
  {
    const int ks = wave;
    float4 f0 = *(const float4*)&pbuf[c32*64 + ks*16 + g32*8];
    float4 f1 = *(const float4*)&pbuf[c32*64 + ks*16 + g32*8 + 4];
    uint32_t p[8] = { packsplit(f0.x), packsplit(f0.y), packsplit(f0.z), packsplit(f0.w),
                      packsplit(f1.x), packsplit(f1.y), packsplit(f1.z), packsplit(f1.w) };
    *(uint4*)&fkFrag[((ks*2+0)*64 + lane)*4] = mkfrag8(p, SELHI);
    *(uint4*)&fkFrag[((ks*2+1)*64 + lane)*4] = mkfrag8(p, SELLO);
    const int t = wave;
    uint32_t q[8];
    #pragma unroll
    for (int j = 0; j < 8; ++j) {
      int h = (g32*8 + j) & 7;
      q[j] = packsplit(pbuf[512 + h*128 + t*32 + c32]);
    }
    *(uint4*)&vFrag[((t*2+0)*64 + lane)*4] = mkfrag8(q, SELHI);
    *(uint4*)&vFrag[((t*2+1)*64 + lane)*4] = mkfrag8(q, SELLO);
  }
  __syncthreads();

  f32x16 Zv;
  #pragma unroll
  for (int r = 0; r < 16; ++r) Zv[r] = 0.f;
  f32x16 aD00 = Zv, aD01 = Zv, aD10 = Zv, aD11 = Zv;
  float n2a[32];
  #pragma unroll
  for (int k = 0; k < 32; ++k) n2a[k] = 0.f;

  const float* aRow0 = addresses + (size_t)(wave*512 + c32) * 64;
  const float* mRow0 = memories + ((size_t)b*2048 + wave*512 + c32) * 64;
  const uint32_t* qaBase = qaF + (size_t)(wave*16)*2048 + lane*4;

  // phase D: single-bf16 operands; 4 MFMAs per 16-row chunk.
  auto do_mfma = [&](int base) {
    uint32_t f0[4], f1[4], n0[4], n1[4];
    #pragma unroll
    for (int e = 0; e < 4; ++e) {
      const int r0 = (base + g32*8 + 2*e) * 68;
      const int r1 = r0 + 68;
      f0[e] = (uint32_t)pF16[r0 + c32]      | ((uint32_t)pF16[r1 + c32] << 16);
      f1[e] = (uint32_t)pF16[r0 + 32 + c32] | ((uint32_t)pF16[r1 + 32 + c32] << 16);
      n0[e] = (uint32_t)pN16[r0 + c32]      | ((uint32_t)pN16[r1 + c32] << 16);
      n1[e] = (uint32_t)pN16[r0 + 32 + c32] | ((uint32_t)pN16[r1 + 32 + c32] << 16);
    }
    uint4 A0 = make_uint4(f0[0], f0[1], f0[2], f0[3]);
    uint4 A1 = make_uint4(f1[0], f1[1], f1[2], f1[3]);
    uint4 B0 = make_uint4(n0[0], n0[1], n0[2], n0[3]);
    uint4 B1 = make_uint4(n1[0], n1[1], n1[2], n1[3]);
    aD00 = mf(A0, B0, aD00);
    aD01 = mf(A0, B1, aD01);
    aD10 = mf(A1, B0, aD10);
    aD11 = mf(A1, B1, aD11);
  };

  // B-MFMAs from the qa table: loads interleaved per-ks (8 regs live).
#define QATAB_B(QP, ACC) do {                                          \
    _Pragma("unroll")                                                  \
    for (int ks = 0; ks < 4; ++ks) {                                   \
      uint4 qh_ = *(const uint4*)((QP) + (ks*2+0)*256);                \
      uint4 ql_ = *(const uint4*)((QP) + (ks*2+1)*256);                \
      uint4 Ah_ = *(uint4*)&fkFrag[((ks*2+0)*64 + lane)*4];            \
      uint4 Al_ = *(uint4*)&fkFrag[((ks*2+1)*64 + lane)*4];            \
      ACC = mf(Ah_, qh_, ACC); ACC = mf(Ah_, ql_, ACC); ACC = mf(Al_, qh_, ACC); \
    } } while(0)

  // elementwise for one 32-col half; aC already carries num*rden.
  // Sigmoid via v_rcp. Outputs RNE bf16, b64-written to pk tiles.
#define ELEM(T2, ACU, ACW) do {                                        \
    unsigned short* rowF_ = pF16 + c32*68;                             \
    unsigned short* rowN_ = pN16 + c32*68;                             \
    _Pragma("unroll")                                                  \
    for (int rq = 0; rq < 4; ++rq) {                                   \
      uint32_t pf_[4], pn_[4];                                         \
      _Pragma("unroll")                                                \
      for (int i = 0; i < 4; ++i) {                                    \
        const int r = rq*4 + i;                                        \
        float upd = ACU[r];                                            \
        float wx  = ACW[r];                                            \
        float wp  = __builtin_amdgcn_rcpf(1.f + __expf(-wx));          \
        float mv  = F4C(M_[(T2)*4 + rq], i);                           \
        float av  = F4C(E_[rq & 1], i);                                \
        float nm  = fmaf(wp, upd - mv, mv);                            \
        float fv  = fmaxf(nm + av, 0.f);                               \
        n2a[(T2)*16 + r] += fv;                                        \
        pn_[i] = bf16rne(nm);                                          \
        pf_[i] = bf16rne(fv);                                          \
      }                                                                \
      if (rq == 1) { E_[0] = *(const float4*)(ap0 + (T2)*32 + 16 + g32*4);      \
                     E_[1] = *(const float4*)(ap0 + (T2)*32 + 16 + g32*4 + 8); }\
      const int col = 32*(T2) + 8*rq + 4*g32;                          \
      *(uint2*)&rowF_[col] = make_uint2(pf_[0] | (pf_[1]<<16), pf_[2] | (pf_[3]<<16)); \
      *(uint2*)&rowN_[col] = make_uint2(pn_[0] | (pn_[1]<<16), pn_[2] | (pn_[3]<<16)); \
    } } while(0)

  // ---- prologue: B(0) + M(0) ----
  f32x16 aBcur = Zv, aBnext;
  float4 M_[8];
  QATAB_B(qaBase, aBcur);
  #pragma unroll
  for (int k = 0; k < 8; ++k) M_[k] = *(const float4*)(mRow0 + k*8 + g32*4);

  #pragma unroll 1
  for (int ss = 0; ss < 16; ++ss) {
    asm volatile("" ::: "memory");  // block LICM of loop-invariant LDS reads

    // ---- 1. finish B(ss): S, den; rden folded into S-fragment ----
    float s0 = aBcur[0], s1 = aBcur[1], s2 = aBcur[2], s3 = aBcur[3];
    float own = (s0 + s1) + (s2 + s3);
    float den = own + __shfl_xor(own, 32) + EPSF;
    float rden = __builtin_amdgcn_rcpf(den);
    float p0 = __shfl_xor(s0, 32), p1 = __shfl_xor(s1, 32),
          p2 = __shfl_xor(s2, 32), p3 = __shfl_xor(s3, 32);
    float rm = (g32 == 0) ? rden : 0.f;   // K-pad mask * rden
    uint32_t sp[8] = { packsplit(s0*rm), packsplit(s1*rm), packsplit(s2*rm), packsplit(s3*rm),
                       packsplit(p0*rm), packsplit(p1*rm), packsplit(p2*rm), packsplit(p3*rm) };
    uint4 Sh = mkfrag8(sp, SELHI), Sl = mkfrag8(sp, SELLO);

    // ---- 2. C-MFMAs, first half (e-tiles 0 and 2) ----
    f32x16 aC0 = Zv, aC2 = Zv;
    {
      uint4 Vh, Vl;
      Vh = *(uint4*)&vFrag[(0*64 + lane)*4]; Vl = *(uint4*)&vFrag[(1*64 + lane)*4];
      aC0 = mf(Vh, Sh, aC0); aC0 = mf(Vh, Sl, aC0); aC0 = mf(Vl, Sh, aC0);
      Vh = *(uint4*)&vFrag[(4*64 + lane)*4]; Vl = *(uint4*)&vFrag[(5*64 + lane)*4];
      aC2 = mf(Vh, Sh, aC2); aC2 = mf(Vh, Sl, aC2); aC2 = mf(Vl, Sh, aC2);
    }

    // ---- 3. pipeline: B-MFMAs for ss+1 (per-ks interleaved loads) ----
    aBnext = Zv;
    if (ss < 15) {
      const uint32_t* qp = qaBase + (size_t)(ss+1)*2048;
      QATAB_B(qp, aBnext);
    }

    // ---- 4. ELEM half 0 (lazy E loads, L1-hot) ----
    const float* ap0 = aRow0 + (size_t)ss * 2048;
    float4 E_[2];
    E_[0] = *(const float4*)(ap0 + g32*4);
    E_[1] = *(const float4*)(ap0 + g32*4 + 8);
    ELEM(0, aC0, aC2);

    // ---- 5. C-MFMAs, second half (e-tiles 1 and 3) ----
    f32x16 aC1 = Zv, aC3 = Zv;
    {
      uint4 Vh, Vl;
      Vh = *(uint4*)&vFrag[(2*64 + lane)*4]; Vl = *(uint4*)&vFrag[(3*64 + lane)*4];
      aC1 = mf(Vh, Sh, aC1); aC1 = mf(Vh, Sl, aC1); aC1 = mf(Vl, Sh, aC1);
      Vh = *(uint4*)&vFrag[(6*64 + lane)*4]; Vl = *(uint4*)&vFrag[(7*64 + lane)*4];
      aC3 = mf(Vh, Sh, aC3); aC3 = mf(Vh, Sl, aC3); aC3 = mf(Vl, Sh, aC3);
    }

    // ---- 6. M_[0..3] <- ss+1 (HBM stream) ----
    if (ss < 15) {
      const float* mp = mRow0 + (size_t)(ss+1) * 2048;
      #pragma unroll
      for (int k = 0; k < 4; ++k) M_[k] = *(const float4*)(mp + k*8 + g32*4);
    }

    // ---- 7. ELEM half 1 ----
    E_[0] = *(const float4*)(ap0 + 32 + g32*4);
    E_[1] = *(const float4*)(ap0 + 32 + g32*4 + 8);
    ELEM(1, aC1, aC3);

    // ---- 8. M_[4..7] <- ss+1 ----
    if (ss < 15) {
      const float* mp = mRow0 + (size_t)(ss+1) * 2048;
      #pragma unroll
      for (int k = 4; k < 8; ++k) M_[k] = *(const float4*)(mp + k*8 + g32*4);
    }

    // ---- 9. phase D: both 16-row chunks (DS + MFMA only) ----
    asm volatile("" ::: "memory");
    do_mfma(0);
    do_mfma(16);

    aBcur = aBnext;
  }

  // ================= epilogue =================
  __syncthreads();   // everyone done with fkFrag/vFrag/pk

  float* n2stageF = (float*)SH;            // [4][64]
  float* norm2F   = ((float*)SH) + 256;    // [64]
  float* den2F    = ((float*)SH) + 320;    // [8]
  float* stageF   = (float*)pkbase;        // [4][16][66]
  const float* fqg = proj + (size_t)b * 2048 + 1536;

  #pragma unroll
  for (int k = 0; k < 32; ++k) {
    float v = n2a[k];
    v += __shfl_xor(v, 1); v += __shfl_xor(v, 2); v += __shfl_xor(v, 4);
    v += __shfl_xor(v, 8); v += __shfl_xor(v, 16);
    n2a[k] = v;
  }
  if (c32 == 0) {
    #pragma unroll
    for (int t2 = 0; t2 < 2; ++t2)
      #pragma unroll
      for (int r = 0; r < 16; ++r) {
        const int j = 32*t2 + 8*(r>>2) + (r&3) + 4*g32;
        n2stageF[wave*64 + j] = n2a[t2*16 + r];
      }
  }
  __syncthreads();
  if (tid < 64)
    norm2F[tid] = (n2stageF[tid] + n2stageF[64+tid]) + (n2stageF[128+tid] + n2stageF[192+tid]);
  __syncthreads();
  if (tid < 8) {
    float s = 0.f;
    for (int d = 0; d < 64; ++d) s = fmaf(fqg[tid*64 + d], norm2F[d], s);
    den2F[tid] = s + EPSF;
  }

  const int hh = tid >> 5;
  const int ee = (tid & 31) * 2;
  float num2a = 0.f, num2b = 0.f;
  #pragma unroll
  for (int p = 0; p < 4; ++p) {
    const int ti = p >> 1, rh = p & 1;
    #pragma unroll
    for (int q = 0; q < 8; ++q) {
      const int rr = (q & 3) + 8*((q >> 2) & 1) + 4*g32;
      const int r = rh*8 + q;
      float v0 = (ti == 0) ? aD00[r] : aD10[r];
      float v1 = (ti == 0) ? aD01[r] : aD11[r];
      stageF[wave*1056 + rr*66 + c32]      = v0;
      stageF[wave*1056 + rr*66 + 32 + c32] = v1;
    }
    __syncthreads();
    #pragma unroll 8
    for (int dl = 0; dl < 16; ++dl) {
      float2 q0 = *(const float2*)&stageF[0*1056 + dl*66 + ee];
      float2 q1 = *(const float2*)&stageF[1*1056 + dl*66 + ee];
      float2 q2 = *(const float2*)&stageF[2*1056 + dl*66 + ee];
      float2 q3 = *(const float2*)&stageF[3*1056 + dl*66 + ee];
      float v0 = (q0.x + q1.x) + (q2.x + q3.x);
      float v1 = (q0.y + q1.y) + (q2.y + q3.y);
      float fv = fqg[hh*64 + p*16 + dl];
      num2a = fmaf(fv, v0, num2a);
      num2b = fmaf(fv, v1, num2b);
    }
    __syncthreads();
  }
  float rd2 = __builtin_amdgcn_rcpf(den2F[hh]);
  attn[(size_t)b*512 + hh*64 + ee]     = num2a * rd2;
  attn[(size_t)b*512 + hh*64 + ee + 1] = num2b * rd2;
#undef ELEM
#undef QATAB_B
}

// =====================================================================
// Kernel 3: out = attn(512x512) @ Wm(512x1024) + bm (unchanged)
// =====================================================================
__global__ __launch_bounds__(256) void out_gemm_kernel(
    const float* __restrict__ A, const float* __restrict__ Wm,
    const float* __restrict__ bm, float* __restrict__ out)
{
  __shared__ float As[16][68];
  __shared__ float Bs[16][68];
  const int col0 = blockIdx.x * 64;
  const int row0 = blockIdx.y * 64;
  const int tid = threadIdx.x;
  const int tr = tid >> 4, tc = tid & 15;
  float acc[4][4] = {};
  for (int k0 = 0; k0 < 512; k0 += 16) {
    {
      int r = tid >> 2, kk = (tid & 3) << 2;
      float4 a4 = *(const float4*)&A[(size_t)(row0 + r) * 512 + k0 + kk];
      As[kk+0][r] = a4.x; As[kk+1][r] = a4.y; As[kk+2][r] = a4.z; As[kk+3][r] = a4.w;
    }
    {
      int kr = tid >> 4, cc = (tid & 15) << 2;
      *(float4*)&Bs[kr][cc] = *(const float4*)&Wm[(size_t)(k0 + kr) * 1024 + col0 + cc];
    }
    __syncthreads();
    #pragma unroll
    for (int k = 0; k < 16; ++k) {
      float4 av4 = *(const float4*)&As[k][tr*4];
      float4 bv4 = *(const float4*)&Bs[k][tc*4];
      float av[4] = {av4.x, av4.y, av4.z, av4.w};
      float bb[4] = {bv4.x, bv4.y, bv4.z, bv4.w};
      #pragma unroll
      for (int i = 0; i < 4; ++i)
        #pragma unroll
        for (int j = 0; j < 4; ++j)
          acc[i][j] = fmaf(av[i], bb[j], acc[i][j]);
    }
    __syncthreads();
  }
  #pragma unroll
  for (int i = 0; i < 4; ++i) {
    int r = row0 + tr*4 + i;
    #pragma unroll
    for (int j = 0; j < 4; ++j) {
      int c = col0 + tc*4 + j;
      out[(size_t)r * 1024 + c] = acc[i][j] + bm[c];
    }
  }
}

extern "C" void kernel_launch(void* const* d_in, const int* in_sizes, int n_in,
                              void* d_out, int out_size, void* d_ws, size_t ws_size,
                              hipStream_t stream)
{
  const float* x    = (const float*)d_in[0];
  const float* mem  = (const float*)d_in[1];
  const float* addr = (const float*)d_in[2];
  const float* Wk   = (const float*)d_in[3];
  const float* bk   = (const float*)d_in[4];
  const float* Wv   = (const float*)d_in[5];
  const float* bv   = (const float*)d_in[6];
  const float* Wq   = (const float*)d_in[7];
  const float* bq   = (const float*)d_in[8];
  const float* Wm   = (const float*)d_in[9];
  const float* bm   = (const float*)d_in[10];
  float* out  = (float*)d_out;
  float* ws   = (float*)d_ws;
  float* proj = ws;                          // 512*2048 floats (4 MB)
  float* attn = ws + (size_t)512 * 2048;     // 512*512 floats (1 MB)
  uint32_t* qaF = (uint32_t*)(ws + (size_t)512 * 2048 + (size_t)512 * 512);  // 512 KB

  hipLaunchKernelGGL(qa_pack_kernel, dim3(64), dim3(64), 0, stream,
                     addr, qaF);
  hipLaunchKernelGGL(proj_gemm_kernel, dim3(32, 8), dim3(256), 0, stream,
                     x, Wk, bk, Wv, bv, Wq, bq, proj);
  hipLaunchKernelGGL(fused_mem_kernel, dim3(512), dim3(256), 0, stream,
                     mem, addr, proj, qaF, attn);
  hipLaunchKernelGGL(out_gemm_kernel, dim3(16, 8), dim3(256), 0, stream,
                     attn, Wm, bm, out);
}